// Round 1
// baseline (786.301 us; speedup 1.0000x reference)
//
#include <hip/hip_runtime.h>
#include <stdint.h>

// InstanceSampling: greedy per-class radius suppression (exact reference semantics).
// B=2, N=8192, C=3, L=16384. RADII = {0.5, 0.6, 0.7}, radius indexed by the
// global pick ordinal i (reference quirk: RADII[sorted_labels[i]], i = loop counter).

#define L_TOT 16384
#define NPT   8192

__device__ __forceinline__ int cellco(float v) {
    int c = (int)floorf((v + 6.4f) * 1.25f);   // cell size 0.8 >= max radius 0.7
    return c < 0 ? 0 : (c > 15 ? 15 : c);
}

// ---------------- k0: init ws ----------------
__global__ void k0_init(int* __restrict__ sample, int* __restrict__ cellcnt,
                        int* __restrict__ cellfill, int* __restrict__ vcount) {
    int t = blockIdx.x * blockDim.x + threadIdx.x;
    if (t < 2 * L_TOT) sample[t] = 0;
    if (t < 8192) { cellcnt[t] = 0; cellfill[t] = 0; }
    if (t == 0) vcount[0] = 0;
}

// ---------------- k1: per-point keys ----------------
__global__ void k1_keys(const float* __restrict__ cls, uint64_t* __restrict__ keys,
                        uint8_t* __restrict__ umeta, int* __restrict__ vcount) {
    int l = blockIdx.x * blockDim.x + threadIdx.x;
    if (l >= L_TOT) return;
    float c0 = cls[l * 3 + 0], c1 = cls[l * 3 + 1], c2 = cls[l * 3 + 2];
    float m = c0; int lab = 0;
    if (c1 > m) { m = c1; lab = 1; }   // strict > : first-max, matches jnp.argmax
    if (c2 > m) { m = c2; lab = 2; }
    int valid = (m >= 0.0f) ? 1 : 0;   // sigmoid(m) >= 0.5  <=>  m >= 0
    float keyf = valid ? m : -__builtin_inff();
    uint32_t u = __float_as_uint(keyf);
    uint32_t o = (u & 0x80000000u) ? ~u : (u | 0x80000000u); // order-preserving map
    // ascending sort by ((~o)<<32 | l) == descending by score, ties by index (stable)
    keys[l] = ((uint64_t)(~o) << 32) | (uint32_t)l;
    umeta[l] = (uint8_t)(lab | (valid << 2));
    if (valid) atomicAdd(vcount, 1);
}

// ---------------- k2: O(L^2) rank sort + build sorted arrays + cell counts ----
__global__ void __launch_bounds__(256) k2_sort(
    const uint64_t* __restrict__ keys, const uint8_t* __restrict__ umeta,
    const float* __restrict__ xyz,
    float4* __restrict__ spts, uint8_t* __restrict__ slab, uint16_t* __restrict__ sorder,
    uint16_t* __restrict__ cellid, int* __restrict__ cellcnt) {
    __shared__ uint64_t tile[2048];
    __shared__ int psum[256];
    const int t = threadIdx.x;
    const int elem = t & 31, part = t >> 5;
    const int l = blockIdx.x * 32 + elem;
    const uint64_t myk = keys[l];
    int cnt = 0;
    for (int t0 = 0; t0 < L_TOT; t0 += 2048) {
        for (int j = t; j < 2048; j += 256) tile[j] = keys[t0 + j];
        __syncthreads();
        const int b0 = part * 256;
        #pragma unroll 4
        for (int j = 0; j < 256; ++j) cnt += (tile[b0 + j] < myk) ? 1 : 0;
        __syncthreads();
    }
    psum[t] = cnt;
    __syncthreads();
    if (t < 32) {
        int rank = 0;
        #pragma unroll
        for (int q = 0; q < 8; ++q) rank += psum[q * 32 + t];
        const int ll = blockIdx.x * 32 + t;
        int b = ll >> 13, p = ll & (NPT - 1);
        const float* src = xyz + ((size_t)(b * NPT + p)) * 3;
        float x = src[0], y = src[1], z = src[2];
        uint8_t mt = umeta[ll];
        int lab = mt & 3, valid = (mt >> 2) & 1;
        float4 v; v.x = x; v.y = y; v.z = z;
        v.w = __uint_as_float((uint32_t)(b | (valid << 1)));
        spts[rank] = v;
        slab[rank] = (uint8_t)lab;
        sorder[rank] = (uint16_t)ll;
        if (valid) {
            int cx = cellco(x), cy = cellco(y), cz = cellco(z);
            int cl = (b << 12) | (cz << 8) | (cy << 4) | cx;
            cellid[rank] = (uint16_t)cl;
            atomicAdd(&cellcnt[cl], 1);
        } else {
            cellid[rank] = 0xFFFFu;
        }
    }
}

// ---------------- g2: exclusive scan of cell counts ----------------
__global__ void g2_scan(const int* __restrict__ cellcnt, int* __restrict__ cellstart) {
    __shared__ int part[256];
    __shared__ int poff[256];
    int t = threadIdx.x;
    int base = t * 32;
    int s = 0;
    for (int k = 0; k < 32; ++k) s += cellcnt[base + k];
    part[t] = s;
    __syncthreads();
    if (t == 0) {
        int run = 0;
        for (int q = 0; q < 256; ++q) { poff[q] = run; run += part[q]; }
    }
    __syncthreads();
    int run = poff[t];
    for (int k = 0; k < 32; ++k) { cellstart[base + k] = run; run += cellcnt[base + k]; }
}

// ---------------- g3: scatter sorted positions into cell lists ----------------
__global__ void g3_scatter(const uint16_t* __restrict__ cellid, const int* __restrict__ cellstart,
                           int* __restrict__ cellfill, uint16_t* __restrict__ cellpts) {
    int pos = blockIdx.x * blockDim.x + threadIdx.x;
    if (pos >= L_TOT) return;
    uint16_t cl = cellid[pos];
    if (cl == 0xFFFFu) return;
    int slot = atomicAdd(&cellfill[cl], 1);
    cellpts[cellstart[cl] + slot] = (uint16_t)pos;
}

// ---------------- k3: windowed greedy (single block) ----------------
__global__ void __launch_bounds__(1024) k3_greedy(
    const float4* __restrict__ spts, const uint8_t* __restrict__ slab,
    const uint16_t* __restrict__ sorder,
    const int* __restrict__ cellstart, const int* __restrict__ cellcnt,
    const uint16_t* __restrict__ cellpts,
    const int* __restrict__ vcount, int* __restrict__ sample) {
    __shared__ uint32_t rem[512];          // remaining bitmask by sorted position
    __shared__ uint8_t  labl[L_TOT];       // labels by sorted position (for radius quirk)
    __shared__ int      win_pos[64];
    __shared__ float4   wdat[64];
    __shared__ float4   pickd[64];         // x,y,z,r2
    __shared__ int      pick_pos[64];
    __shared__ int      pick_i[64];
    __shared__ int      pick_b[64];
    __shared__ int      s_nwin, s_npick, s_i;

    const int t = threadIdx.x;
    const int V = vcount[0];
    for (int j = t; j < L_TOT; j += 1024) labl[j] = slab[j];
    for (int w = t; w < 512; w += 1024) {
        int lo = w * 32;
        uint32_t m;
        if (V >= lo + 32) m = 0xFFFFFFFFu;
        else if (V <= lo) m = 0u;
        else m = (1u << (V - lo)) - 1u;
        rem[w] = m;   // valid points occupy sorted positions [0, V)
    }
    if (t == 0) s_i = 0;
    __syncthreads();

    for (int round = 0; round < L_TOT; ++round) {
        // --- A: gather next up-to-64 remaining positions (wave 0) ---
        if (t < 64) {
            int cnt = 0;
            #pragma unroll
            for (int q = 0; q < 8; ++q) cnt += __popc(rem[t * 8 + q]);
            int pre = cnt;
            #pragma unroll
            for (int off = 1; off < 64; off <<= 1) {
                int nb = __shfl_up(pre, off);
                if (t >= off) pre += nb;
            }
            int r = pre - cnt;     // exclusive prefix
            if (t == 63) s_nwin = (pre < 64) ? pre : 64;
            if (r < 64) {
                for (int q = 0; q < 8 && r < 64; ++q) {
                    uint32_t wv = rem[t * 8 + q];
                    while (wv && r < 64) {
                        int b = __builtin_ctz(wv);
                        wv &= wv - 1;
                        win_pos[r] = (t * 8 + q) * 32 + b;
                        ++r;
                    }
                }
            }
        }
        __syncthreads();
        const int nwin = s_nwin;
        if (nwin == 0) break;
        // --- B: load window candidate data ---
        if (t < 64) {
            float4 v = make_float4(0.f, 0.f, 0.f, 0.f);
            if (t < nwin) v = spts[win_pos[t]];
            wdat[t] = v;
        }
        __syncthreads();
        // --- C: exact serial resolve within window (wave 0) ---
        if (t < 64) {
            float4 v = wdat[t];
            int myb = (int)(__float_as_uint(v.w) & 1u);
            bool alive = (t < nwin);
            unsigned long long am = __ballot(alive ? 1 : 0);
            int np = 0, ii = s_i;
            while (am) {
                int jp = __builtin_ctzll(am);
                float px = __shfl(v.x, jp);
                float py = __shfl(v.y, jp);
                float pz = __shfl(v.z, jp);
                int   pb = __shfl(myb, jp);
                int lb = labl[ii];
                float rr = (lb == 0) ? 0.5f : ((lb == 1) ? 0.6f : 0.7f);
                float r2 = __fmul_rn(rr, rr);
                if (t == jp) {
                    pickd[np] = make_float4(v.x, v.y, v.z, r2);
                    pick_pos[np] = win_pos[t];
                    pick_i[np] = ii;
                    pick_b[np] = myb;
                }
                ++ii; ++np;
                if (alive && t > jp && myb == pb) {
                    float dx = __fsub_rn(v.x, px);
                    float dy = __fsub_rn(v.y, py);
                    float dz = __fsub_rn(v.z, pz);
                    float d2 = __fadd_rn(__fadd_rn(__fmul_rn(dx, dx), __fmul_rn(dy, dy)),
                                         __fmul_rn(dz, dz));
                    if (d2 <= r2) alive = false;
                }
                unsigned long long bal = __ballot(alive ? 1 : 0);
                unsigned long long mask = (jp >= 63) ? 0ull : (~0ull << (jp + 1));
                am = bal & mask;
            }
            if (t == 0) { s_npick = np; s_i = ii; }
        }
        __syncthreads();
        const int npick = s_npick;
        // --- D1: record outputs for this round's picks ---
        if (t < npick) {
            int pos = pick_pos[t];
            int orig = (int)sorder[pos];
            int b = orig >> 13;
            int p = orig & (NPT - 1);
            sample[b * L_TOT + pick_i[t]] = p;
        }
        // --- D2: grid-based suppression of remaining points ---
        const int ntask = npick * 27 * 4;   // 4-way sub-split of cell lists for balance
        for (int task = t; task < ntask; task += 1024) {
            int sub = task & 3;
            int pc = task >> 2;
            int p = pc / 27;
            int c = pc - p * 27;
            int ox = c % 3 - 1, oy = (c / 3) % 3 - 1, oz = c / 9 - 1;
            float4 pv = pickd[p];
            int cx = cellco(pv.x) + ox, cy = cellco(pv.y) + oy, cz = cellco(pv.z) + oz;
            if (cx < 0 || cx > 15 || cy < 0 || cy > 15 || cz < 0 || cz > 15) continue;
            int cl = (pick_b[p] << 12) | (cz << 8) | (cy << 4) | cx;
            int st = cellstart[cl], cn = cellcnt[cl];
            float r2 = pv.w;
            for (int k = sub; k < cn; k += 4) {
                int q = (int)cellpts[st + k];
                uint32_t bit = 1u << (q & 31);
                if (rem[q >> 5] & bit) {
                    float4 qv = spts[q];
                    float dx = __fsub_rn(qv.x, pv.x);
                    float dy = __fsub_rn(qv.y, pv.y);
                    float dz = __fsub_rn(qv.z, pv.z);
                    float d2 = __fadd_rn(__fadd_rn(__fmul_rn(dx, dx), __fmul_rn(dy, dy)),
                                         __fmul_rn(dz, dz));
                    if (d2 <= r2) atomicAnd(&rem[q >> 5], ~bit);
                }
            }
        }
        __syncthreads();
    }
}

// ---------------- k4: write outputs ----------------
__global__ void k4_out(const float* __restrict__ xyz, const int* __restrict__ sample,
                       float* __restrict__ out) {
    int s = blockIdx.x * blockDim.x + threadIdx.x;
    if (s >= 2 * L_TOT) return;
    int idx = sample[s];
    int b = s >> 14;
    const float* src = xyz + ((size_t)(b * NPT + idx)) * 3;
    float* dst = out + (size_t)s * 3;
    dst[0] = src[0]; dst[1] = src[1]; dst[2] = src[2];
    out[3 * 2 * L_TOT + s] = (float)idx;   // sample_idx as float32 values
}

extern "C" void kernel_launch(void* const* d_in, const int* in_sizes, int n_in,
                              void* d_out, int out_size, void* d_ws, size_t ws_size,
                              hipStream_t stream) {
    const float* xyz = (const float*)d_in[0];
    const float* cls = (const float*)d_in[1];
    float* out = (float*)d_out;
    char* ws = (char*)d_ws;
    uint64_t* keys    = (uint64_t*)(ws + 0);        // 131072
    float4*   spts    = (float4*)  (ws + 131072);   // 262144
    uint8_t*  slab    = (uint8_t*) (ws + 393216);   // 16384
    uint16_t* sorder  = (uint16_t*)(ws + 409600);   // 32768
    uint16_t* cellid  = (uint16_t*)(ws + 442368);   // 32768
    int*      cellcnt = (int*)     (ws + 475136);   // 32768
    int*      cellst  = (int*)     (ws + 507904);   // 32768
    int*      cellfil = (int*)     (ws + 540672);   // 32768
    uint16_t* cellpts = (uint16_t*)(ws + 573440);   // 32768
    int*      sample  = (int*)     (ws + 606208);   // 131072
    int*      vcount  = (int*)     (ws + 737280);   // 256
    uint8_t*  umeta   = (uint8_t*) (ws + 737536);   // 16384

    k0_init   <<<128, 256, 0, stream>>>(sample, cellcnt, cellfil, vcount);
    k1_keys   <<<64,  256, 0, stream>>>(cls, keys, umeta, vcount);
    k2_sort   <<<512, 256, 0, stream>>>(keys, umeta, xyz, spts, slab, sorder, cellid, cellcnt);
    g2_scan   <<<1,   256, 0, stream>>>(cellcnt, cellst);
    g3_scatter<<<64,  256, 0, stream>>>(cellid, cellst, cellfil, cellpts);
    k3_greedy <<<1,  1024, 0, stream>>>(spts, slab, sorder, cellst, cellcnt, cellpts, vcount, sample);
    k4_out    <<<128, 256, 0, stream>>>(xyz, sample, out);
}

// Round 2
// 597.459 us; speedup vs baseline: 1.3161x; 1.3161x over previous
//
#include <hip/hip_runtime.h>
#include <stdint.h>

// InstanceSampling: greedy per-class radius suppression (exact reference semantics).
// B=2, N=8192, C=3, L=16384. RADII = {0.5,0.6,0.7}; radius of pick #i is
// RADII[label of sorted slot i] (reference quirk: indexed by pick ORDINAL).
//
// Pipeline: k0 init -> k1 keys -> k2 O(L^2) rank sort -> g2 scan -> g3 cell
// scatter -> k3 greedy (single block, software-pipelined: wave0 resolves
// window t+1 while waves 1..15 apply suppression of pick-list t) -> k4 out.

#define L_TOT 16384
#define NPT   8192

__device__ __forceinline__ int cellco(float v) {
    int c = (int)floorf((v + 6.4f) * 1.25f);   // cell size 0.8 >= max radius 0.7
    return c < 0 ? 0 : (c > 15 ? 15 : c);
}

// ---------------- k0: init ws ----------------
__global__ void k0_init(uint16_t* __restrict__ sample, int* __restrict__ cellcnt,
                        int* __restrict__ vcount) {
    int t = blockIdx.x * blockDim.x + threadIdx.x;
    if (t < 16384) ((int*)sample)[t] = 0;        // 2*L_TOT u16 = 16384 ints
    if (t < 8192) cellcnt[t] = 0;
    if (t == 0) vcount[0] = 0;
}

// ---------------- k1: per-point keys ----------------
__global__ void k1_keys(const float* __restrict__ cls, uint64_t* __restrict__ keys,
                        uint8_t* __restrict__ umeta, int* __restrict__ vcount) {
    int l = blockIdx.x * blockDim.x + threadIdx.x;
    if (l >= L_TOT) return;
    float c0 = cls[l * 3 + 0], c1 = cls[l * 3 + 1], c2 = cls[l * 3 + 2];
    float m = c0; int lab = 0;
    if (c1 > m) { m = c1; lab = 1; }   // strict > : first-max, matches jnp.argmax
    if (c2 > m) { m = c2; lab = 2; }
    int valid = (m >= 0.0f) ? 1 : 0;   // sigmoid(m) >= 0.5  <=>  m >= 0
    float keyf = valid ? m : -__builtin_inff();
    uint32_t u = __float_as_uint(keyf);
    uint32_t o = (u & 0x80000000u) ? ~u : (u | 0x80000000u); // order-preserving map
    keys[l] = ((uint64_t)(~o) << 32) | (uint32_t)l;          // asc == desc score, stable
    umeta[l] = (uint8_t)(lab | (valid << 2));
    if (valid) atomicAdd(vcount, 1);
}

// ---------------- k2: O(L^2) rank sort + build sorted arrays + cell counts ----
__global__ void __launch_bounds__(256) k2_sort(
    const uint64_t* __restrict__ keys, const uint8_t* __restrict__ umeta,
    const float* __restrict__ xyz,
    float4* __restrict__ spts, uint8_t* __restrict__ slab, uint16_t* __restrict__ sorder,
    int* __restrict__ cellcnt) {
    __shared__ uint64_t tile[2048];
    __shared__ int psum[256];
    const int t = threadIdx.x;
    const int elem = t & 31, part = t >> 5;
    const int l = blockIdx.x * 32 + elem;
    const uint64_t myk = keys[l];
    int cnt = 0;
    for (int t0 = 0; t0 < L_TOT; t0 += 2048) {
        for (int j = t; j < 2048; j += 256) tile[j] = keys[t0 + j];
        __syncthreads();
        const int b0 = part * 256;
        #pragma unroll 4
        for (int j = 0; j < 256; ++j) cnt += (tile[b0 + j] < myk) ? 1 : 0;
        __syncthreads();
    }
    psum[t] = cnt;
    __syncthreads();
    if (t < 32) {
        int rank = 0;
        #pragma unroll
        for (int q = 0; q < 8; ++q) rank += psum[q * 32 + t];
        const int ll = blockIdx.x * 32 + t;
        int b = ll >> 13, p = ll & (NPT - 1);
        const float* src = xyz + ((size_t)(b * NPT + p)) * 3;
        float x = src[0], y = src[1], z = src[2];
        uint8_t mt = umeta[ll];
        int lab = mt & 3, valid = (mt >> 2) & 1;
        float4 v; v.x = x; v.y = y; v.z = z;
        v.w = __uint_as_float((uint32_t)(b | (valid << 1)));
        spts[rank] = v;
        slab[rank] = (uint8_t)lab;
        sorder[rank] = (uint16_t)ll;
        if (valid) {
            int cl = (b << 12) | (cellco(z) << 8) | (cellco(y) << 4) | cellco(x);
            atomicAdd(&cellcnt[cl], 1);
        }
    }
}

// ---------------- g2: exclusive scan (8193 entries) + zero counts for reuse --
__global__ void g2_scan(int* __restrict__ cellcnt, int* __restrict__ cellstart) {
    __shared__ int part[256];
    __shared__ int poff[256];
    int t = threadIdx.x;
    int base = t * 32;
    int loc[32];
    int s = 0;
    for (int k = 0; k < 32; ++k) { loc[k] = cellcnt[base + k]; s += loc[k]; }
    part[t] = s;
    __syncthreads();
    if (t == 0) {
        int run = 0;
        for (int q = 0; q < 256; ++q) { poff[q] = run; run += part[q]; }
    }
    __syncthreads();
    int run = poff[t];
    for (int k = 0; k < 32; ++k) {
        cellstart[base + k] = run; run += loc[k];
        cellcnt[base + k] = 0;               // reuse as fill counters in g3
    }
    if (t == 255) cellstart[8192] = run;     // sentinel = V
}

// ---------------- g3: scatter coords into cell-ordered float4 list ----------
__global__ void g3_scatter(const float4* __restrict__ spts, const int* __restrict__ cellstart,
                           int* __restrict__ cellfill, float4* __restrict__ cellxyz) {
    int pos = blockIdx.x * blockDim.x + threadIdx.x;
    if (pos >= L_TOT) return;
    float4 v = spts[pos];
    uint32_t w = __float_as_uint(v.w);
    if (!(w & 2u)) return;                   // invalid
    int b = (int)(w & 1u);
    int cl = (b << 12) | (cellco(v.z) << 8) | (cellco(v.y) << 4) | cellco(v.x);
    int slot = atomicAdd(&cellfill[cl], 1);
    float4 o; o.x = v.x; o.y = v.y; o.z = v.z; o.w = __uint_as_float((uint32_t)pos);
    cellxyz[cellstart[cl] + slot] = o;
}

// ---------------- k3: pipelined windowed greedy (single block) ---------------
// Phase p (cur = p&1): wave0 gathers top-64 remaining (snapshot), patches them
// against in-flight pick list pkd[cur], wave-serially resolves -> pkd[cur^1],
// writes sample outputs. Waves 1..15 concurrently apply pkd[cur] suppression
// to the rem bitmask via cell lists. One barrier per phase.
__global__ void __launch_bounds__(1024) k3_greedy(
    const float4* __restrict__ spts, const uint8_t* __restrict__ slab,
    const uint16_t* __restrict__ sorder,
    const int* __restrict__ cellstart, const float4* __restrict__ cellxyz,
    const int* __restrict__ vcount, uint16_t* __restrict__ sample) {
    __shared__ uint32_t rem[512];            // remaining bitmask by sorted position
    __shared__ uint16_t cs16[8193];          // cellstart (u16), sentinel at [8192]
    __shared__ float4   pkd[2][64];          // x,y,z,r2 (double-buffered pick lists)
    __shared__ int      pkb[2][64];          // pick batch
    __shared__ int      pkn[2];
    __shared__ int      win_pos[64];
    __shared__ int      s_done;

    const int t = threadIdx.x;
    const int V = vcount[0];
    for (int j = t; j < 8193; j += 1024) cs16[j] = (uint16_t)cellstart[j];
    for (int w = t; w < 512; w += 1024) {
        int lo = w * 32;
        uint32_t m;
        if (V >= lo + 32) m = 0xFFFFFFFFu;
        else if (V <= lo) m = 0u;
        else m = (1u << (V - lo)) - 1u;
        rem[w] = m;                          // valid points occupy positions [0, V)
    }
    if (t < 2) pkn[t] = 0;
    if (t == 0) s_done = 0;
    __syncthreads();

    int ii = 0;                              // pick ordinal (uniform in wave 0)
    for (int phase = 0; phase < 32768; ++phase) {
        const int cur = phase & 1, nx = cur ^ 1;
        if (t < 64) {
            // ---- wave 0: snapshot-gather / patch / serial resolve ----
            uint32_t wv[8];
            int cnt = 0;
            #pragma unroll
            for (int q = 0; q < 8; ++q) {
                wv[q] = ((volatile uint32_t*)rem)[t * 8 + q];
                cnt += __popc(wv[q]);
            }
            int pre = cnt;
            #pragma unroll
            for (int off = 1; off < 64; off <<= 1) {
                int nb = __shfl_up(pre, off);
                if (t >= off) pre += nb;
            }
            const int total = __shfl(pre, 63);
            if (total == 0) {
                if (t == 0) { s_done = 1; pkn[nx] = 0; }
            } else {
                int r = pre - cnt;           // exclusive prefix
                if (r < 64) {
                    #pragma unroll
                    for (int q = 0; q < 8; ++q) {
                        if (r >= 64) break;
                        uint32_t m = wv[q];
                        while (m && r < 64) {
                            int b = __builtin_ctz(m);
                            m &= m - 1;
                            win_pos[r] = (t * 8 + q) * 32 + b;
                            ++r;
                        }
                    }
                }
                __builtin_amdgcn_wave_barrier();
                asm volatile("s_waitcnt lgkmcnt(0)" ::: "memory");
                __builtin_amdgcn_wave_barrier();
                const int nwin = total < 64 ? total : 64;
                const bool inw = (t < nwin);
                float4 v = make_float4(1e30f, 1e30f, 1e30f, 0.0f);
                int ord = 0;
                if (inw) {
                    int pos = win_pos[t];
                    v = spts[pos];
                    ord = (int)sorder[pos];
                }
                const int myb = (int)(__float_as_uint(v.w) & 1u);
                // radius-by-ordinal sequence for the next 64 ordinals
                int oi = ii + t;
                int lb = slab[oi < L_TOT ? oi : (L_TOT - 1)];
                float rr = (lb == 0) ? 0.5f : ((lb == 1) ? 0.6f : 0.7f);
                float r2s = __fmul_rn(rr, rr);
                // patch against in-flight pick list (covers the rem race)
                bool alive = inw;
                const int npp = pkn[cur];
                for (int j = 0; j < npp; ++j) {
                    float4 pk = pkd[cur][j];
                    if (pkb[cur][j] == myb) {
                        float dx = __fsub_rn(v.x, pk.x);
                        float dy = __fsub_rn(v.y, pk.y);
                        float dz = __fsub_rn(v.z, pk.z);
                        float d2 = __fadd_rn(__fadd_rn(__fmul_rn(dx, dx), __fmul_rn(dy, dy)),
                                             __fmul_rn(dz, dz));
                        if (d2 <= pk.w) alive = false;
                    }
                }
                // wave-serial exact resolve
                unsigned long long am = __ballot(alive ? 1 : 0);
                int np = 0;
                while (am) {
                    int jp = (int)__builtin_ctzll(am);
                    float px = __shfl(v.x, jp);
                    float py = __shfl(v.y, jp);
                    float pz = __shfl(v.z, jp);
                    int   pb = __shfl(myb, jp);
                    float r2 = __shfl(r2s, np);
                    if (t == jp) {
                        pkd[nx][np] = make_float4(v.x, v.y, v.z, r2);
                        pkb[nx][np] = myb;
                        sample[myb * L_TOT + ii + np] = (uint16_t)(ord & (NPT - 1));
                    }
                    if (alive && t > jp && myb == pb) {
                        float dx = __fsub_rn(v.x, px);
                        float dy = __fsub_rn(v.y, py);
                        float dz = __fsub_rn(v.z, pz);
                        float d2 = __fadd_rn(__fadd_rn(__fmul_rn(dx, dx), __fmul_rn(dy, dy)),
                                             __fmul_rn(dz, dz));
                        if (d2 <= r2) alive = false;
                    }
                    ++np;
                    unsigned long long bal = __ballot(alive ? 1 : 0);
                    am = (jp >= 63) ? 0ull : (bal & (~0ull << (jp + 1)));
                }
                ii += np;
                if (t == 0) pkn[nx] = np;
            }
        } else {
            // ---- waves 1..15: apply in-flight pick list pkd[cur] ----
            const int np = pkn[cur];
            if (np > 0) {
                const int tid = t - 64;                  // 0..959
                const int ntask = np * 216;              // 27 cells x 8-way split
                for (int task = tid; task < ntask; task += 960) {
                    int sub = task & 7;
                    int pc = task >> 3;
                    int p = pc / 27;
                    int c = pc - p * 27;
                    float4 pv = pkd[cur][p];
                    int pb_ = pkb[cur][p];
                    float r2 = pv.w;
                    int cx = cellco(pv.x) + (c % 3) - 1;
                    int cy = cellco(pv.y) + ((c / 3) % 3) - 1;
                    int cz = cellco(pv.z) + (c / 9) - 1;
                    if ((unsigned)cx > 15u || (unsigned)cy > 15u || (unsigned)cz > 15u) continue;
                    // conservative cell-box cull (margin >> f32 ulp)
                    float lox = -6.4f + 0.8f * cx, hix = lox + 0.8f;
                    float loy = -6.4f + 0.8f * cy, hiy = loy + 0.8f;
                    float loz = -6.4f + 0.8f * cz, hiz = loz + 0.8f;
                    if (cx == 0) lox = -1e30f;  if (cx == 15) hix = 1e30f;
                    if (cy == 0) loy = -1e30f;  if (cy == 15) hiy = 1e30f;
                    if (cz == 0) loz = -1e30f;  if (cz == 15) hiz = 1e30f;
                    float dx = fmaxf(fmaxf(lox - pv.x, pv.x - hix), 0.0f);
                    float dy = fmaxf(fmaxf(loy - pv.y, pv.y - hiy), 0.0f);
                    float dz = fmaxf(fmaxf(loz - pv.z, pv.z - hiz), 0.0f);
                    if (dx * dx + dy * dy + dz * dz > r2 + 0.02f) continue;
                    int cl = (pb_ << 12) | (cz << 8) | (cy << 4) | cx;
                    int st = (int)cs16[cl];
                    int en = (int)cs16[cl + 1];
                    for (int k = st + sub; k < en; k += 8) {
                        float4 q = cellxyz[k];
                        float ddx = __fsub_rn(q.x, pv.x);
                        float ddy = __fsub_rn(q.y, pv.y);
                        float ddz = __fsub_rn(q.z, pv.z);
                        float d2 = __fadd_rn(__fadd_rn(__fmul_rn(ddx, ddx), __fmul_rn(ddy, ddy)),
                                             __fmul_rn(ddz, ddz));
                        if (d2 <= r2) {
                            uint32_t qp = __float_as_uint(q.w);
                            atomicAnd(&rem[qp >> 5], ~(1u << (qp & 31)));
                        }
                    }
                }
            }
        }
        __syncthreads();
        if (s_done) break;
    }
}

// ---------------- k4: write outputs ----------------
__global__ void k4_out(const float* __restrict__ xyz, const uint16_t* __restrict__ sample,
                       float* __restrict__ out) {
    int s = blockIdx.x * blockDim.x + threadIdx.x;
    if (s >= 2 * L_TOT) return;
    int idx = (int)sample[s];
    int b = s >> 14;
    const float* src = xyz + ((size_t)(b * NPT + idx)) * 3;
    float* dst = out + (size_t)s * 3;
    dst[0] = src[0]; dst[1] = src[1]; dst[2] = src[2];
    out[3 * 2 * L_TOT + s] = (float)idx;   // sample_idx as float32 values
}

extern "C" void kernel_launch(void* const* d_in, const int* in_sizes, int n_in,
                              void* d_out, int out_size, void* d_ws, size_t ws_size,
                              hipStream_t stream) {
    const float* xyz = (const float*)d_in[0];
    const float* cls = (const float*)d_in[1];
    float* out = (float*)d_out;
    char* ws = (char*)d_ws;
    // layout (total 708864 B):
    float4*   spts    = (float4*)  (ws + 0);        // 262144
    uint8_t*  slab    = (uint8_t*) (ws + 262144);   // 16384
    uint16_t* sorder  = (uint16_t*)(ws + 278528);   // 32768
    int*      cellcnt = (int*)     (ws + 311296);   // 32768 (reused as fill counters)
    int*      cellst  = (int*)     (ws + 344064);   // 36864 (8193 ints + pad)
    float4*   cellxyz = (float4*)  (ws + 380928);   // 262144
    uint64_t* keys    = (uint64_t*)(ws + 380928);   // alias: dead after k2
    uint8_t*  umeta   = (uint8_t*) (ws + 512000);   // alias: dead after k2
    uint16_t* sample  = (uint16_t*)(ws + 643072);   // 65536
    int*      vcount  = (int*)     (ws + 708608);   // 256

    k0_init   <<<128, 256, 0, stream>>>(sample, cellcnt, vcount);
    k1_keys   <<<64,  256, 0, stream>>>(cls, keys, umeta, vcount);
    k2_sort   <<<512, 256, 0, stream>>>(keys, umeta, xyz, spts, slab, sorder, cellcnt);
    g2_scan   <<<1,   256, 0, stream>>>(cellcnt, cellst);
    g3_scatter<<<64,  256, 0, stream>>>(spts, cellst, cellcnt, cellxyz);
    k3_greedy <<<1,  1024, 0, stream>>>(spts, slab, sorder, cellst, cellxyz, vcount, sample);
    k4_out    <<<128, 256, 0, stream>>>(xyz, sample, out);
}